// Round 4
// baseline (6198.265 us; speedup 1.0000x reference)
//
#include <hip/hip_runtime.h>
#include <hip/hip_bf16.h>

// Problem constants
#define NROWS 2048
#define HDIM  4096
#define VDIM  32000
#define KTILES (HDIM / 64)  // 64 K-tiles of BK=64

typedef __attribute__((ext_vector_type(8))) __bf16 bf16x8;
typedef __attribute__((ext_vector_type(4))) float floatx4;
typedef __attribute__((ext_vector_type(8))) unsigned short ushort8;

__device__ __forceinline__ unsigned short f2bf(float x) {
  unsigned u = __builtin_bit_cast(unsigned, x);
  return (unsigned short)((u + 0x7fffu + ((u >> 16) & 1u)) >> 16);  // RNE
}
__device__ __forceinline__ float bf2f(unsigned short h) {
  return __builtin_bit_cast(float, (unsigned)h << 16);
}

__device__ __forceinline__ void ld_lds16(const void* g, void* l) {
  __builtin_amdgcn_global_load_lds(
      (const __attribute__((address_space(1))) void*)g,
      (__attribute__((address_space(3))) void*)l, 16, 0, 0);
}

#define MFMA __builtin_amdgcn_mfma_f32_16x16x32_bf16
#define BAR() __builtin_amdgcn_s_barrier()
#define WAITL0() asm volatile("s_waitcnt lgkmcnt(0)" ::: "memory")
#define WAITV0() asm volatile("s_waitcnt vmcnt(0)" ::: "memory")
#define WAITV10() asm volatile("s_waitcnt vmcnt(10)" ::: "memory")
#define WAITV12() asm volatile("s_waitcnt vmcnt(12)" ::: "memory")
#define WAITV18() asm volatile("s_waitcnt vmcnt(18)" ::: "memory")
#define MEMSEP() asm volatile("" ::: "memory")

// ---------------------------------------------------------------------------
// fp32 -> bf16 cast, grid-stride, 32B in / 16B out per lane (inputs only now)
__global__ __launch_bounds__(256) void cvt_kernel(const float4* __restrict__ in,
                                                  ushort8* __restrict__ out, int n8) {
  for (int i = blockIdx.x * 256 + threadIdx.x; i < n8; i += gridDim.x * 256) {
    float4 v0 = in[2 * i];
    float4 v1 = in[2 * i + 1];
    ushort8 o = {f2bf(v0.x), f2bf(v0.y), f2bf(v0.z), f2bf(v0.w),
                 f2bf(v1.x), f2bf(v1.y), f2bf(v1.z), f2bf(v1.w)};
    out[i] = o;
  }
}

// zero the output scalar + both rowsum arrays (4096 floats, contiguous)
__global__ __launch_bounds__(256) void zero_init(float* __restrict__ rs,
                                                 float* __restrict__ out) {
  const int i = blockIdx.x * 256 + threadIdx.x;
  if (i < 2 * NROWS) rs[i] = 0.0f;
  if (i == 0) out[0] = 0.0f;
}

// ---------------------------------------------------------------------------
// 256x256-tile 8-phase GEMM with FUSED fp32->bf16 B conversion + softmax denom.
// C[m][v] = sum_k A[m][k](bf16) * Bf[v][k](fp32, cast bf16) + bias[v].
// A staging: global_load_lds (pre-swizzled source, linear LDS dest) as before.
// B staging: reg-staged (T14): ph1/ph2 issue fp32 global loads for tile T+2;
// ph3/ph4 cvt+swizzled-ds_write the regs loaded 6 phases earlier (tile T+1).
// vmcnt discipline (in-order retirement, m135): per tile, issue order is
//   ph1: [2 ld_lds UA2(T+1)] [4 fp32 rB1(T+2)]
//   ph2: [2 ld_lds UA1(T+2)] [4 fp32 rB2(T+2)]
// waits: ph3 vmcnt(18) -> rB1(T+1) done; ph4 vmcnt(12) -> rB2(T+1) done;
// tile-end vmcnt(10) -> UA2(T+1) landed, T+2 loads stay in flight.
// ds_write visibility: write at T ph3/ph4, first read at T+1 ph1/ph2; writer's
// lgkmcnt(0) (next WAITL0) precedes a barrier that precedes the reads.
__global__ __launch_bounds__(512, 1) void gemm_fused(const unsigned short* __restrict__ A,
                                                     const float* __restrict__ Bf,
                                                     const float* __restrict__ bias,
                                                     unsigned short* __restrict__ C,
                                                     float* __restrict__ rowsum) {
  extern __shared__ __align__(16) char smem[];  // 131072 B at launch
  const int t = threadIdx.x;
  const int wave = t >> 6;
  const int lane = t & 63;
  const int quad = lane >> 4;
  const int l16 = lane & 15;
  const int waveN = wave & 3;   // 4 N-quarters of 64
  const int waveM = wave >> 2;  // 2 M-halves of 128

  // XCD-aware bijective swizzle (grid=1000, 1000%8==0); M fastest within XCD.
  const int bid = blockIdx.x;
  const int wgid = (bid & 7) * 125 + (bid >> 3);
  const int m0 = (wgid & 7) * 256;
  const int v0 = (wgid >> 3) * 256;

  // ---- A staging pointers (bf16 source, pre-swizzled; linear ld_lds dest) ----
  const int j0r = t >> 3;
  const int sl = t & 7;
  const char* pA1[2]; const char* pA2[2];
#pragma unroll
  for (int j = 0; j < 2; j++) {
    const int rr = j * 64 + j0r;
    const int swz = ((sl ^ (rr & 7)) << 4);
    const int ga1 = (rr & 63) + ((rr >> 6) << 7);  // UA1 global row map
    pA1[j] = (const char*)(A + (size_t)(m0 + ga1) * HDIM) + swz;
    pA2[j] = (const char*)(A + (size_t)(m0 + ga1 + 64) * HDIM) + swz;
  }
  char* ldst = smem + wave * 1024;  // wave-uniform LDS base; HW adds lane*16
  auto STAGE_A = [&](char* dst, const char* const* pj, int kt) {
    ld_lds16(pj[0] + (size_t)kt * 128, dst);
    ld_lds16(pj[1] + (size_t)kt * 128, dst + 8192);
  };

  // ---- B fp32 reg-staging: LINEAR global source, swizzle applied at ds_write.
  // thread covers unit rows rr0=t/8, rr1=64+t/8, 8-float slot sl=t&7.
  const int rr0 = j0r, rr1 = 64 + j0r;
  const int gb0 = (rr0 & 31) + ((rr0 >> 5) << 6);  // UB1 global row map
  const int gb1 = (rr1 & 31) + ((rr1 >> 5) << 6);
  const float4* pB1j0 = (const float4*)(Bf + (size_t)(v0 + gb0) * HDIM) + sl * 2;
  const float4* pB1j1 = (const float4*)(Bf + (size_t)(v0 + gb1) * HDIM) + sl * 2;
  const float4* pB2j0 = (const float4*)(Bf + (size_t)(v0 + gb0 + 32) * HDIM) + sl * 2;
  const float4* pB2j1 = (const float4*)(Bf + (size_t)(v0 + gb1 + 32) * HDIM) + sl * 2;
  // swizzled ds_write byte offsets (within dbuf half, incl. unit base)
  const int woB1_0 = 32768 + rr0 * 128 + ((sl ^ (rr0 & 7)) << 4);
  const int woB1_1 = 32768 + rr1 * 128 + ((sl ^ (rr1 & 7)) << 4);
  const int woB2_0 = woB1_0 + 16384;
  const int woB2_1 = woB1_1 + 16384;
  auto pack8 = [&](const float4& lo, const float4& hi) {
    ushort8 o = {f2bf(lo.x), f2bf(lo.y), f2bf(lo.z), f2bf(lo.w),
                 f2bf(hi.x), f2bf(hi.y), f2bf(hi.z), f2bf(hi.w)};
    return o;
  };

  // ---- fragment read addressing (swizzled; unchanged from verified r2) ----
  const int sx = l16 & 7;
  const int sk0 = ((0 * 4 + quad) ^ sx) << 4;
  const int sk1 = ((1 * 4 + quad) ^ sx) << 4;
  const char* lrdA = smem + (waveM * 64 + l16) * 128;
  const char* lrdB = smem + 32768 + (waveN * 32 + l16) * 128;

  floatx4 acc[8][4] = {};
  bf16x8 a[4][2];
  bf16x8 b0[2][2];
  bf16x8 b1[2][2];

  // B-reg generations (all named; no runtime indexing — rule #20)
  float4 A10, A11, A12, A13, A20, A21, A22, A23;  // gen A
  float4 B10, B11, B12, B13, B20, B21, B22, B23;  // gen B

  // ---- prologue: tile0 staged fully; gen A primed with rB(1); UA1(1) issued.
  STAGE_A(ldst + 0, pA1, 0);
  STAGE_A(ldst + 16384, pA2, 0);
  MEMSEP();
  {
    float4 t10 = pB1j0[0], t11 = pB1j0[1], t12 = pB1j1[0], t13 = pB1j1[1];
    float4 t20 = pB2j0[0], t21 = pB2j0[1], t22 = pB2j1[0], t23 = pB2j1[1];
    *(ushort8*)(smem + woB1_0) = pack8(t10, t11);
    *(ushort8*)(smem + woB1_1) = pack8(t12, t13);
    *(ushort8*)(smem + woB2_0) = pack8(t20, t21);
    *(ushort8*)(smem + woB2_1) = pack8(t22, t23);
  }
  WAITV0();  // UA1(0), UA2(0) landed
  MEMSEP();
  A10 = pB1j0[16]; A11 = pB1j0[17]; A12 = pB1j1[16]; A13 = pB1j1[17];
  MEMSEP();
  STAGE_A(ldst + 65536 + 0, pA1, 1);  // UA1(1)
  MEMSEP();
  A20 = pB2j0[16]; A21 = pB2j0[17]; A22 = pB2j1[16]; A23 = pB2j1[17];
  WAITL0();  // drain prologue ds_writes before publishing barrier
  BAR();

  auto tileBody = [&](int dOff, int T,
                      float4& c10, float4& c11, float4& c12, float4& c13,
                      float4& c20, float4& c21, float4& c22, float4& c23,
                      float4& p10, float4& p11, float4& p12, float4& p13,
                      float4& p20, float4& p21, float4& p22, float4& p23) {
    const bool s1 = (T + 1 < KTILES);
    const bool s2 = (T + 2 < KTILES);
    const int oOff = 65536 - dOff;  // other dbuf half
    // ---- phase 1: q(m0-3, n0-1) | issue UA2(T+1), rB1(T+2) ----
#pragma unroll
    for (int m = 0; m < 4; m++) {
      a[m][0] = *(const bf16x8*)(lrdA + dOff + m * 2048 + sk0);
      a[m][1] = *(const bf16x8*)(lrdA + dOff + m * 2048 + sk1);
    }
#pragma unroll
    for (int n = 0; n < 2; n++) {
      b0[n][0] = *(const bf16x8*)(lrdB + dOff + n * 2048 + sk0);
      b0[n][1] = *(const bf16x8*)(lrdB + dOff + n * 2048 + sk1);
    }
    if (s1) STAGE_A(ldst + oOff + 16384, pA2, T + 1);
    MEMSEP();
    if (s2) {
      p10 = pB1j0[(T + 2) * 16];     p11 = pB1j0[(T + 2) * 16 + 1];
      p12 = pB1j1[(T + 2) * 16];     p13 = pB1j1[(T + 2) * 16 + 1];
    }
    BAR();
    WAITL0();
    __builtin_amdgcn_s_setprio(1);
#pragma unroll
    for (int ks = 0; ks < 2; ks++)
#pragma unroll
      for (int m = 0; m < 4; m++)
#pragma unroll
        for (int n = 0; n < 2; n++)
          acc[m][n] = MFMA(a[m][ks], b0[n][ks], acc[m][n], 0, 0, 0);
    __builtin_amdgcn_s_setprio(0);
    BAR();
    // ---- phase 2: q(m0-3, n2-3) | issue UA1(T+2), rB2(T+2) ----
#pragma unroll
    for (int n = 0; n < 2; n++) {
      b1[n][0] = *(const bf16x8*)(lrdB + dOff + 16384 + n * 2048 + sk0);
      b1[n][1] = *(const bf16x8*)(lrdB + dOff + 16384 + n * 2048 + sk1);
    }
    if (s2) STAGE_A(ldst + dOff + 0, pA1, T + 2);  // UA1(T) last read ph1
    MEMSEP();
    if (s2) {
      p20 = pB2j0[(T + 2) * 16];     p21 = pB2j0[(T + 2) * 16 + 1];
      p22 = pB2j1[(T + 2) * 16];     p23 = pB2j1[(T + 2) * 16 + 1];
    }
    BAR();
    WAITL0();
    __builtin_amdgcn_s_setprio(1);
#pragma unroll
    for (int ks = 0; ks < 2; ks++)
#pragma unroll
      for (int m = 0; m < 4; m++)
#pragma unroll
        for (int n = 0; n < 2; n++)
          acc[m][2 + n] = MFMA(a[m][ks], b1[n][ks], acc[m][2 + n], 0, 0, 0);
    __builtin_amdgcn_s_setprio(0);
    BAR();
    // ---- phase 3: q(m4-7, n0-1) | cvt+write UB1(T+1) into other half ----
#pragma unroll
    for (int m = 0; m < 4; m++) {
      a[m][0] = *(const bf16x8*)(lrdA + dOff + 16384 + m * 2048 + sk0);
      a[m][1] = *(const bf16x8*)(lrdA + dOff + 16384 + m * 2048 + sk1);
    }
    if (s2) { WAITV18(); } else if (s1) { WAITV0(); }
    if (s1) {
      *(ushort8*)(smem + oOff + woB1_0) = pack8(c10, c11);
      *(ushort8*)(smem + oOff + woB1_1) = pack8(c12, c13);
    }
    BAR();
    WAITL0();
    __builtin_amdgcn_s_setprio(1);
#pragma unroll
    for (int ks = 0; ks < 2; ks++)
#pragma unroll
      for (int m = 0; m < 4; m++)
#pragma unroll
        for (int n = 0; n < 2; n++)
          acc[4 + m][n] = MFMA(a[m][ks], b0[n][ks], acc[4 + m][n], 0, 0, 0);
    __builtin_amdgcn_s_setprio(0);
    BAR();
    // ---- phase 4: q(m4-7, n2-3) | cvt+write UB2(T+1); tile-end vmcnt ----
    if (s2) { WAITV12(); } else if (s1) { WAITV0(); }
    if (s1) {
      *(ushort8*)(smem + oOff + woB2_0) = pack8(c20, c21);
      *(ushort8*)(smem + oOff + woB2_1) = pack8(c22, c23);
    }
    BAR();
    __builtin_amdgcn_s_setprio(1);
#pragma unroll
    for (int ks = 0; ks < 2; ks++)
#pragma unroll
      for (int m = 0; m < 4; m++)
#pragma unroll
        for (int n = 0; n < 2; n++)
          acc[4 + m][2 + n] = MFMA(a[m][ks], b1[n][ks], acc[4 + m][2 + n], 0, 0, 0);
    __builtin_amdgcn_s_setprio(0);
    if (s2) { WAITV10(); } else if (s1) { WAITV0(); }
    BAR();
  };

  for (int T = 0; T < KTILES; T += 2) {
    tileBody(0, T, A10, A11, A12, A13, A20, A21, A22, A23,
             B10, B11, B12, B13, B20, B21, B22, B23);
    tileBody(65536, T + 1, B10, B11, B12, B13, B20, B21, B22, B23,
             A10, A11, A12, A13, A20, A21, A22, A23);
  }

  // ---- epilogue: C write + per-row sum(exp) (fused softmax denominator) ----
  float rsum[8][4];
#pragma unroll
  for (int m = 0; m < 8; m++)
#pragma unroll
    for (int r = 0; r < 4; r++) rsum[m][r] = 0.0f;

#pragma unroll
  for (int n = 0; n < 4; n++) {
    const int colv = v0 + waveN * 64 + n * 16 + l16;
    const float bv = bias[colv];
#pragma unroll
    for (int m = 0; m < 8; m++) {
      const int rbase = m0 + waveM * 128 + m * 16 + quad * 4;
#pragma unroll
      for (int r = 0; r < 4; r++) {
        const float v = acc[m][n][r] + bv;
        C[(size_t)(rbase + r) * VDIM + colv] = f2bf(v);
        rsum[m][r] += __expf(v);
      }
    }
  }
#pragma unroll
  for (int off = 1; off < 16; off <<= 1)
#pragma unroll
    for (int m = 0; m < 8; m++)
#pragma unroll
      for (int r = 0; r < 4; r++) rsum[m][r] += __shfl_xor(rsum[m][r], off);

  __syncthreads();  // all waves past K-loop; safe to reuse smem
  float(*smred)[4] = (float(*)[4])smem;  // [256 rows][4 waveN]
  if (l16 == 0) {
#pragma unroll
    for (int m = 0; m < 8; m++)
#pragma unroll
      for (int r = 0; r < 4; r++)
        smred[waveM * 128 + m * 16 + quad * 4 + r][waveN] = rsum[m][r];
  }
  __syncthreads();
  if (t < 256) {
    const float s = smred[t][0] + smred[t][1] + smred[t][2] + smred[t][3];
    atomicAdd(&rowsum[m0 + t], s);  // device-scope: XCD-safe
  }
}

// ---------------------------------------------------------------------------
// Single-pass generalized JSD (beta = 0.5), batchmean. One block per row;
// logZ = log(rowsum) precomputed in the GEMM epilogue (fp32-accurate).
__global__ __launch_bounds__(256) void jsd_row(const unsigned short* __restrict__ Ls,
                                               const unsigned short* __restrict__ Lt,
                                               const float* __restrict__ rsS,
                                               const float* __restrict__ rsT,
                                               float* __restrict__ out) {
  const int row = blockIdx.x;
  const unsigned short* ps = Ls + (size_t)row * VDIM;
  const unsigned short* pt = Lt + (size_t)row * VDIM;
  const float zs = __logf(rsS[row]);
  const float zt = __logf(rsT[row]);
  float local = 0.f;
  for (int c = threadIdx.x * 8; c < VDIM; c += 2048) {
    ushort8 a = *(const ushort8*)(ps + c);
    ushort8 b = *(const ushort8*)(pt + c);
#pragma unroll
    for (int j = 0; j < 8; j++) {
      float lq = bf2f(a[j]) - zs;  // student log-softmax
      float lp = bf2f(b[j]) - zt;  // teacher log-softmax
      float q = __expf(lq);
      float p = __expf(lp);
      float lm = __logf(0.5f * (p + q));
      local += 0.5f * (p * (lp - lm) + q * (lq - lm));
    }
  }
#pragma unroll
  for (int off = 32; off >= 1; off >>= 1) local += __shfl_down(local, off);
  __shared__ float wred[4];
  const int wv = threadIdx.x >> 6;
  if ((threadIdx.x & 63) == 0) wred[wv] = local;
  __syncthreads();
  if (threadIdx.x == 0) {
    atomicAdd(out, (wred[0] + wred[1] + wred[2] + wred[3]) * (1.0f / (float)NROWS));
  }
}

// ---------------------------------------------------------------------------
extern "C" void kernel_launch(void* const* d_in, const int* in_sizes, int n_in,
                              void* d_out, int out_size, void* d_ws, size_t ws_size,
                              hipStream_t stream) {
  const float* s_in = (const float*)d_in[0];
  const float* t_in = (const float*)d_in[1];
  const float* W_s = (const float*)d_in[2];
  const float* b_s = (const float*)d_in[3];
  const float* W_t = (const float*)d_in[4];
  const float* b_t = (const float*)d_in[5];
  float* out = (float*)d_out;

  // workspace layout (wsW region now unused; offsets kept stable):
  //   sA/tA : bf16 inputs                                 2x 16,777,216
  //   Lsb/Ltb: bf16 logits                               2x 131,072,000
  //   rowsumS/rowsumT : per-row sum(exp(logit))          2x 8,192
  char* ws = (char*)d_ws;
  unsigned short* sA = (unsigned short*)(ws + 262144000);
  unsigned short* tA = (unsigned short*)(ws + 278921216);
  unsigned short* Lsb = (unsigned short*)(ws + 295698432);
  unsigned short* Ltb = (unsigned short*)(ws + 426770432);
  float* rowsumS = (float*)(ws + 557842432);
  float* rowsumT = rowsumS + NROWS;

  static bool lds_opted = false;
  if (!lds_opted) {
    (void)hipFuncSetAttribute((const void*)gemm_fused,
                              hipFuncAttributeMaxDynamicSharedMemorySize, 131072);
    lds_opted = true;
  }

  zero_init<<<dim3(16), dim3(256), 0, stream>>>(rowsumS, out);

  cvt_kernel<<<dim3(2048), dim3(256), 0, stream>>>((const float4*)s_in, (ushort8*)sA,
                                                   NROWS * HDIM / 8);
  cvt_kernel<<<dim3(2048), dim3(256), 0, stream>>>((const float4*)t_in, (ushort8*)tA,
                                                   NROWS * HDIM / 8);

  gemm_fused<<<dim3(1000), dim3(512), 131072, stream>>>(sA, W_s, b_s, Lsb, rowsumS);
  gemm_fused<<<dim3(1000), dim3(512), 131072, stream>>>(tA, W_t, b_t, Ltb, rowsumT);

  jsd_row<<<dim3(NROWS), dim3(256), 0, stream>>>(Lsb, Ltb, rowsumS, rowsumT, out);
}